// Round 3
// baseline (58.731 us; speedup 1.0000x reference)
//
#include <hip/hip_runtime.h>

#define PAD_VAL 9999.0f
constexpr int BATCH = 8;
constexpr int NS = 1024;      // support rows
constexpr int NF = 32;        // features
constexpr int NQUANT = 999;   // quantile count
constexpr int NCOL = BATCH * NF;   // 256 columns
constexpr int EPL = 16;            // elements per lane (1024 / 64)

// One WAVE (64 threads) per (b,f) column. 16 elements/lane in registers.
// No __syncthreads anywhere. Bitonic sort: j<16 in-register, j>=16 via shfl_xor.
// Quantile table + binary searches via single-wave LDS (lgkmcnt-ordered).
__global__ __launch_bounds__(64) void fused_wave(const float* __restrict__ xs,
                                                 const float* __restrict__ xq,
                                                 const unsigned char* __restrict__ mraw,
                                                 float* __restrict__ outS,
                                                 float* __restrict__ outQ) {
    __shared__ float s0[NS];       // sorted column
    __shared__ float s1[NS];       // quantile table (999 used)

    const int col = blockIdx.x;
    const int b = col >> 5, f = col & 31;
    const int l = threadIdx.x;     // lane 0..63

    // ---- mask layout detect: scan first 8 KiB (safe for byte-bool/int32/f32) ----
    int l3f = 0, loff = 0;
    {
        const uint4* m4 = (const uint4*)mraw;
        #pragma unroll
        for (int r = 0; r < 8; r++) {
            uint4 d4 = m4[l * 8 + r];
            unsigned w[4] = {d4.x, d4.y, d4.z, d4.w};
            #pragma unroll
            for (int c = 0; c < 4; c++) {
                if ((w[c] >> 24) == 0x3fu) l3f = 1;          // f32 1.0f top byte
                if ((w[c] & 0xFFFFFF00u) != 0u) loff = 1;    // nonzero byte at pos%4!=0
            }
        }
    }
    const int mode = __ballot(l3f) ? 2 : (__ballot(loff) ? 1 : 0); // 2=f32 1=byte 0=int32

    // ---- own 16 mask bits + seq_len ----
    int mk[EPL];
    const int rowbase = b * NS + l * EPL;
    if (mode == 1) {
        uint4 mb = *(const uint4*)(mraw + rowbase);
        unsigned w[4] = {mb.x, mb.y, mb.z, mb.w};
        #pragma unroll
        for (int r = 0; r < EPL; r++) mk[r] = (w[r >> 2] >> ((r & 3) * 8)) & 0xff;
    } else if (mode == 0) {
        const uint4* mi = (const uint4*)mraw;
        #pragma unroll
        for (int c = 0; c < 4; c++) {
            uint4 d4 = mi[(rowbase >> 2) + c];
            mk[c * 4 + 0] = d4.x != 0; mk[c * 4 + 1] = d4.y != 0;
            mk[c * 4 + 2] = d4.z != 0; mk[c * 4 + 3] = d4.w != 0;
        }
    } else {
        const float* mf = (const float*)mraw;
        #pragma unroll
        for (int r = 0; r < EPL; r++) mk[r] = (mf[rowbase + r] != 0.0f);
    }
    int cnt = 0;
    #pragma unroll
    for (int r = 0; r < EPL; r++) cnt += (mk[r] == 0);
    #pragma unroll
    for (int o = 1; o < 64; o <<= 1) cnt += __shfl_xor(cnt, o, 64);
    const float sl = (float)cnt;

    // ---- load support (kept for search) and query (early, latency hidden by sort) ----
    const float* xscol = xs + (size_t)(b * NS) * NF + f;
    const float* xqcol = xq + (size_t)(b * NS) * NF + f;
    float xv[EPL], qv[EPL];
    #pragma unroll
    for (int r = 0; r < EPL; r++) xv[r] = xscol[(l * EPL + r) * NF];
    #pragma unroll
    for (int r = 0; r < EPL; r++) qv[r] = xqcol[(l * EPL + r) * NF];

    float v[EPL];
    #pragma unroll
    for (int r = 0; r < EPL; r++) v[r] = mk[r] ? PAD_VAL : xv[r];

    // ---- bitonic sort over e = (l<<4)|r ----
    for (int k = 2; k <= NS; k <<= 1) {
        for (int j = k >> 1; j > 0; j >>= 1) {
            if (j >= EPL) {
                const int m = j >> 4;
                const bool lower = ((l & m) == 0);
                const bool dir = (((l << 4) & k) == 0);   // e&k depends only on lane bits (k>=32 here)
                const bool keepmin = (lower == dir);
                #pragma unroll
                for (int r = 0; r < EPL; r++) {
                    float o = __shfl_xor(v[r], m, 64);
                    v[r] = keepmin ? fminf(v[r], o) : fmaxf(v[r], o);
                }
            } else {
                #pragma unroll
                for (int r = 0; r < EPL; r++) {
                    if ((r & j) == 0) {
                        const int e = (l << 4) | r;
                        const bool dir = ((e & k) == 0);
                        float a = v[r], c = v[r | j];
                        float mn = fminf(a, c), mx = fmaxf(a, c);
                        v[r]     = dir ? mn : mx;
                        v[r | j] = dir ? mx : mn;
                    }
                }
            }
        }
    }

    // ---- sorted column -> LDS ----
    #pragma unroll
    for (int r = 0; r < EPL; r++) s0[l * EPL + r] = v[r];

    // ---- quantiles (exact reference f32 arithmetic) -> s1 ----
    #pragma unroll
    for (int t = 0; t < EPL; t++) {
        int qi = l + t * 64;               // cyclic: conflict-free s1 writes
        if (qi < NQUANT) {
            float q = (float)(qi + 1) / 1000.0f;
            float idxf = q * (float)(NS - 1);
            int lo = (int)idxf;
            int hi = min(lo + 1, NS - 1);
            float frac = idxf - (float)lo;
            float a = s0[lo], c = s0[hi];
            s1[qi] = a + frac * (c - a);
        }
    }

    // ---- support bucketize: 16 interleaved branchless 10-step searches ----
    int pos[EPL];
    #pragma unroll
    for (int r = 0; r < EPL; r++) pos[r] = 0;
    #pragma unroll
    for (int step = 512; step > 0; step >>= 1) {
        #pragma unroll
        for (int r = 0; r < EPL; r++) {
            int np = pos[r] + step;
            if (np <= NQUANT && s1[np - 1] <= xv[r]) pos[r] = np;
        }
    }

    float sum = 0.0f, sumsq = 0.0f;
    float vs[EPL];
    #pragma unroll
    for (int r = 0; r < EPL; r++) {
        float vv = mk[r] ? 0.0f : (float)pos[r] / sl;
        vs[r] = vv;
        sum += vv; sumsq += vv * vv;
    }
    #pragma unroll
    for (int o = 1; o < 64; o <<= 1) {
        sum   += __shfl_xor(sum, o, 64);
        sumsq += __shfl_xor(sumsq, o, 64);
    }
    const float mean = sum / sl;
    const float var = fmaxf(sumsq / sl - mean * mean, 0.0f);
    const float istd = (var > 0.0f) ? (1.0f / sqrtf(var)) : 0.0f;

    // ---- support output ----
    float* oscol = outS + (size_t)(b * NS) * NF + f;
    #pragma unroll
    for (int r = 0; r < EPL; r++)
        oscol[(l * EPL + r) * NF] = mk[r] ? 0.0f : (vs[r] - mean) * istd;

    // ---- query bucketize + output ----
    int posq[EPL];
    #pragma unroll
    for (int r = 0; r < EPL; r++) posq[r] = 0;
    #pragma unroll
    for (int step = 512; step > 0; step >>= 1) {
        #pragma unroll
        for (int r = 0; r < EPL; r++) {
            int np = posq[r] + step;
            if (np <= NQUANT && s1[np - 1] <= qv[r]) posq[r] = np;
        }
    }
    float* oqcol = outQ + (size_t)(b * NS) * NF + f;
    #pragma unroll
    for (int r = 0; r < EPL; r++)
        oqcol[(l * EPL + r) * NF] = ((float)posq[r] / sl - mean) * istd;
}

extern "C" void kernel_launch(void* const* d_in, const int* in_sizes, int n_in,
                              void* d_out, int out_size, void* d_ws, size_t ws_size,
                              hipStream_t stream) {
    const float* xs = (const float*)d_in[0];
    const float* xq = (const float*)d_in[1];
    const unsigned char* mraw = (const unsigned char*)d_in[2];
    float* out = (float*)d_out;

    fused_wave<<<NCOL, 64, 0, stream>>>(xs, xq, mraw,
                                        out, out + BATCH * NS * NF);
}

// Round 4
// 43.217 us; speedup vs baseline: 1.3590x; 1.3590x over previous
//
#include <hip/hip_runtime.h>

#define PAD_VAL 9999.0f
constexpr int BATCH = 8;
constexpr int NS = 1024;      // support rows
constexpr int NF = 32;        // features
constexpr int NQUANT = 999;   // quantile count
constexpr int NCOL = BATCH * NF;   // 256 columns
constexpr int EPL = 16;            // elements per lane (1024 / 64)

// ---- bitonic network, fully compile-time staged (all register indices constexpr) ----
template<int K, int J>
__device__ __forceinline__ void stages_for_k(float (&v)[EPL], int l) {
    if constexpr (J >= EPL) {
        constexpr int m = J / EPL;                       // lane xor distance
        const bool dir = (((l * EPL) & K) == 0);         // K>=32 here: e&K is lane-only
        const bool keepmin = (((l & m) == 0) == dir);
        #pragma unroll
        for (int r = 0; r < EPL; r++) {
            float o = __shfl_xor(v[r], m, 64);
            v[r] = keepmin ? fminf(v[r], o) : fmaxf(v[r], o);
        }
    } else {
        #pragma unroll
        for (int r = 0; r < EPL; r++) {
            if constexpr (true) {
                if ((r & J) == 0) {
                    const bool dir = ((((l << 4) | r) & K) == 0);
                    float a = v[r], c = v[r | J];
                    float mn = fminf(a, c), mx = fmaxf(a, c);
                    v[r]     = dir ? mn : mx;
                    v[r | J] = dir ? mx : mn;
                }
            }
        }
    }
    if constexpr (J > 1) stages_for_k<K, J / 2>(v, l);
}

template<int K>
__device__ __forceinline__ void bitonic_k(float (&v)[EPL], int l) {
    stages_for_k<K, K / 2>(v, l);
    if constexpr (K < NS) bitonic_k<K * 2>(v, l);
}

// One WAVE per (b,f) column; 16 elements/lane in registers; no __syncthreads.
__global__ __launch_bounds__(64) void fused_wave(const float* __restrict__ xs,
                                                 const float* __restrict__ xq,
                                                 const unsigned char* __restrict__ mraw,
                                                 float* __restrict__ outS,
                                                 float* __restrict__ outQ) {
    __shared__ float s0[NS];       // sorted column
    __shared__ float s1[NS];       // quantile table (999 used)

    const int col = blockIdx.x;
    const int b = col >> 5, f = col & 31;
    const int l = threadIdx.x;     // lane 0..63

    // ---- mask layout detect: scan first 8 KiB (safe for byte-bool/int32/f32) ----
    int l3f = 0, loff = 0;
    {
        const uint4* m4 = (const uint4*)mraw;
        #pragma unroll
        for (int r = 0; r < 8; r++) {
            uint4 d4 = m4[l * 8 + r];
            unsigned w[4] = {d4.x, d4.y, d4.z, d4.w};
            #pragma unroll
            for (int c = 0; c < 4; c++) {
                if ((w[c] >> 24) == 0x3fu) l3f = 1;          // f32 1.0f top byte
                if ((w[c] & 0xFFFFFF00u) != 0u) loff = 1;    // nonzero byte at pos%4!=0
            }
        }
    }
    const int mode = __ballot(l3f) ? 2 : (__ballot(loff) ? 1 : 0); // 2=f32 1=byte 0=int32

    // ---- own 16 mask bits packed into one int + seq_len ----
    unsigned mkbits = 0;
    const int rowbase = b * NS + l * EPL;
    if (mode == 1) {
        uint4 mb = *(const uint4*)(mraw + rowbase);
        unsigned w[4] = {mb.x, mb.y, mb.z, mb.w};
        #pragma unroll
        for (int r = 0; r < EPL; r++)
            mkbits |= (((w[r >> 2] >> ((r & 3) * 8)) & 0xffu) ? 1u : 0u) << r;
    } else if (mode == 0) {
        const uint4* mi = (const uint4*)mraw;
        #pragma unroll
        for (int c = 0; c < 4; c++) {
            uint4 d4 = mi[(rowbase >> 2) + c];
            mkbits |= ((d4.x != 0) << (c * 4 + 0)) | ((d4.y != 0) << (c * 4 + 1))
                    | ((d4.z != 0) << (c * 4 + 2)) | ((d4.w != 0) << (c * 4 + 3));
        }
    } else {
        const float* mf = (const float*)mraw;
        #pragma unroll
        for (int r = 0; r < EPL; r++) mkbits |= ((mf[rowbase + r] != 0.0f) ? 1u : 0u) << r;
    }
    int cnt = EPL - __popc(mkbits);
    #pragma unroll
    for (int o = 1; o < 64; o <<= 1) cnt += __shfl_xor(cnt, o, 64);
    const float sl = (float)cnt;

    // ---- load support + query (query early: HBM latency hidden under sort) ----
    const float* xscol = xs + (size_t)(b * NS) * NF + f;
    const float* xqcol = xq + (size_t)(b * NS) * NF + f;
    float xv[EPL], qv[EPL];
    #pragma unroll
    for (int r = 0; r < EPL; r++) xv[r] = xscol[(l * EPL + r) * NF];
    #pragma unroll
    for (int r = 0; r < EPL; r++) qv[r] = xqcol[(l * EPL + r) * NF];

    float v[EPL];
    #pragma unroll
    for (int r = 0; r < EPL; r++) v[r] = ((mkbits >> r) & 1u) ? PAD_VAL : xv[r];

    // ---- bitonic sort (fully unrolled, register-resident) ----
    bitonic_k<2>(v, l);

    // ---- sorted column -> LDS ----
    #pragma unroll
    for (int r = 0; r < EPL; r++) s0[l * EPL + r] = v[r];

    // ---- quantiles (exact reference f32 arithmetic) -> s1 ----
    #pragma unroll
    for (int t = 0; t < EPL; t++) {
        int qi = l + t * 64;
        if (qi < NQUANT) {
            float q = (float)(qi + 1) / 1000.0f;
            float idxf = q * (float)(NS - 1);
            int lo = (int)idxf;
            int hi = min(lo + 1, NS - 1);
            float frac = idxf - (float)lo;
            float a = s0[lo], c = s0[hi];
            s1[qi] = a + frac * (c - a);
        }
    }

    // ---- support bucketize: 16 interleaved branchless 10-step searches ----
    int pos[EPL];
    #pragma unroll
    for (int r = 0; r < EPL; r++) pos[r] = 0;
    #pragma unroll
    for (int step = 512; step > 0; step >>= 1) {
        #pragma unroll
        for (int r = 0; r < EPL; r++) {
            int np = pos[r] + step;
            if (np <= NQUANT && s1[np - 1] <= xv[r]) pos[r] = np;
        }
    }

    float sum = 0.0f, sumsq = 0.0f;
    float vs[EPL];
    #pragma unroll
    for (int r = 0; r < EPL; r++) {
        float vv = ((mkbits >> r) & 1u) ? 0.0f : (float)pos[r] / sl;
        vs[r] = vv;
        sum += vv; sumsq += vv * vv;
    }
    #pragma unroll
    for (int o = 1; o < 64; o <<= 1) {
        sum   += __shfl_xor(sum, o, 64);
        sumsq += __shfl_xor(sumsq, o, 64);
    }
    const float mean = sum / sl;
    const float var = fmaxf(sumsq / sl - mean * mean, 0.0f);
    const float istd = (var > 0.0f) ? (1.0f / sqrtf(var)) : 0.0f;

    // ---- support output ----
    float* oscol = outS + (size_t)(b * NS) * NF + f;
    #pragma unroll
    for (int r = 0; r < EPL; r++)
        oscol[(l * EPL + r) * NF] = ((mkbits >> r) & 1u) ? 0.0f : (vs[r] - mean) * istd;

    // ---- query bucketize + output ----
    int posq[EPL];
    #pragma unroll
    for (int r = 0; r < EPL; r++) posq[r] = 0;
    #pragma unroll
    for (int step = 512; step > 0; step >>= 1) {
        #pragma unroll
        for (int r = 0; r < EPL; r++) {
            int np = posq[r] + step;
            if (np <= NQUANT && s1[np - 1] <= qv[r]) posq[r] = np;
        }
    }
    float* oqcol = outQ + (size_t)(b * NS) * NF + f;
    #pragma unroll
    for (int r = 0; r < EPL; r++)
        oqcol[(l * EPL + r) * NF] = ((float)posq[r] / sl - mean) * istd;
}

extern "C" void kernel_launch(void* const* d_in, const int* in_sizes, int n_in,
                              void* d_out, int out_size, void* d_ws, size_t ws_size,
                              hipStream_t stream) {
    const float* xs = (const float*)d_in[0];
    const float* xq = (const float*)d_in[1];
    const unsigned char* mraw = (const unsigned char*)d_in[2];
    float* out = (float*)d_out;

    fused_wave<<<NCOL, 64, 0, stream>>>(xs, xq, mraw,
                                        out, out + BATCH * NS * NF);
}

// Round 5
// 18.933 us; speedup vs baseline: 3.1021x; 2.2827x over previous
//
#include <hip/hip_runtime.h>

#define PAD_VAL 9999.0f
constexpr int BATCH = 8;
constexpr int NS = 1024;      // support rows
constexpr int NF = 32;        // features
constexpr int NQUANT = 999;   // quantile count
constexpr int NT = 256;       // threads per block (4 waves)
constexpr int EPL = 4;        // elements per lane (1024 / 256)

// Bitonic network, compile-time staged. EPL=4 so all arrays are tiny (register-resident).
// J>=256: cross-wave via LDS (3 stages). 4<=J<=128: within-wave shfl_xor. J<4: in-register.
template<int K, int J>
__device__ __forceinline__ void bstage(float (&v)[EPL], const int t, float* buf) {
    if constexpr (J >= 64 * EPL) {            // J = 256 or 512: cross-wave
        __syncthreads();                       // protect buf from previous stage's readers
        *(float4*)(buf + t * EPL) = *(const float4*)v;
        __syncthreads();
        float o[EPL] __attribute__((aligned(16)));
        *(float4*)o = *(const float4*)(buf + ((t * EPL) ^ J));
        const bool keepmin = ((((t * EPL) & J) == 0) == (((t * EPL) & K) == 0));
        #pragma unroll
        for (int r = 0; r < EPL; r++)
            v[r] = keepmin ? fminf(v[r], o[r]) : fmaxf(v[r], o[r]);
    } else if constexpr (J >= EPL) {          // J = 4..128: lane xor m = J/4 (<64)
        constexpr int m = J / EPL;
        const bool keepmin = ((((t * EPL) & J) == 0) == (((t * EPL) & K) == 0));
        #pragma unroll
        for (int r = 0; r < EPL; r++) {
            float o = __shfl_xor(v[r], m, 64);
            v[r] = keepmin ? fminf(v[r], o) : fmaxf(v[r], o);
        }
    } else {                                   // J = 1 or 2: in-register
        #pragma unroll
        for (int r = 0; r < EPL; r++) {
            if ((r & J) == 0) {
                const bool dir = (((t * EPL + r) & K) == 0);
                float a = v[r], c = v[r | J];
                float mn = fminf(a, c), mx = fmaxf(a, c);
                v[r]     = dir ? mn : mx;
                v[r | J] = dir ? mx : mn;
            }
        }
    }
    if constexpr (J > 1) bstage<K, J / 2>(v, t, buf);
}

template<int K>
__device__ __forceinline__ void bsort(float (&v)[EPL], const int t, float* buf) {
    bstage<K, K / 2>(v, t, buf);
    if constexpr (K < NS) bsort<K * 2>(v, t, buf);
}

__global__ __launch_bounds__(NT) void fused(const float* __restrict__ xs,
                                            const float* __restrict__ xq,
                                            const unsigned char* __restrict__ mraw,
                                            float* __restrict__ outS,
                                            float* __restrict__ outQ) {
    __shared__ float buf[NS];      // sort exchange + sorted column
    __shared__ float squant[NS];   // quantile table (999 used)
    __shared__ int   flags[2];
    __shared__ int   wcnt[4];
    __shared__ float rstat[8];

    const int t = threadIdx.x;
    const int lane = t & 63, w = t >> 6;
    // XCD-aware: bid%8 = XCD -> give each XCD one full batch (its 32 feature cols)
    const int b = blockIdx.x & 7, f = blockIdx.x >> 3;

    if (t < 2) flags[t] = 0;
    __syncthreads();

    // ---- mask layout detect: scan first 8 KiB (safe for byte-bool/int32/f32) ----
    {
        int l3f = 0, loff = 0;
        const uint4* m4p = (const uint4*)mraw;
        #pragma unroll
        for (int r = 0; r < 2; r++) {
            uint4 d = m4p[t * 2 + r];
            unsigned ws[4] = {d.x, d.y, d.z, d.w};
            #pragma unroll
            for (int c = 0; c < 4; c++) {
                if ((ws[c] >> 24) == 0x3fu) l3f = 1;          // f32 1.0f top byte
                if ((ws[c] & 0xFFFFFF00u) != 0u) loff = 1;    // nonzero high bytes
            }
        }
        if (__ballot(l3f)  && lane == 0) atomicOr(&flags[0], 1);
        if (__ballot(loff) && lane == 0) atomicOr(&flags[1], 1);
    }
    __syncthreads();
    const int mode = flags[0] ? 2 : (flags[1] ? 1 : 0);  // 2=f32 1=byte 0=int32

    // ---- own 4 mask bits + per-wave seq_len partial ----
    unsigned mkbits = 0;
    const int rowbase = b * NS + t * EPL;
    if (mode == 1) {
        unsigned mw = *(const unsigned*)(mraw + rowbase);
        mkbits = ((mw & 0xffu) ? 1u : 0u) | (((mw >> 8) & 0xffu) ? 2u : 0u)
               | (((mw >> 16) & 0xffu) ? 4u : 0u) | (((mw >> 24) & 0xffu) ? 8u : 0u);
    } else if (mode == 0) {
        uint4 d = ((const uint4*)mraw)[b * (NS / 4) + t];
        mkbits = (d.x != 0) | ((d.y != 0) << 1) | ((d.z != 0) << 2) | ((d.w != 0) << 3);
    } else {
        float4 d = ((const float4*)mraw)[b * (NS / 4) + t];
        mkbits = (d.x != 0.0f) | ((d.y != 0.0f) << 1) | ((d.z != 0.0f) << 2) | ((d.w != 0.0f) << 3);
    }
    {
        int cnt = EPL - __popc(mkbits);
        #pragma unroll
        for (int o = 1; o < 64; o <<= 1) cnt += __shfl_xor(cnt, o, 64);
        if (lane == 0) wcnt[w] = cnt;          // visible after the sort's first barrier
    }

    // ---- loads: support (kept) + query (early; in flight during sort) ----
    const float* xscol = xs + (size_t)(b * NS) * NF + f;
    const float* xqcol = xq + (size_t)(b * NS) * NF + f;
    float xv[EPL], qv[EPL];
    #pragma unroll
    for (int r = 0; r < EPL; r++) xv[r] = xscol[(t * EPL + r) * NF];
    #pragma unroll
    for (int r = 0; r < EPL; r++) qv[r] = xqcol[(t * EPL + r) * NF];

    float v[EPL] __attribute__((aligned(16)));
    #pragma unroll
    for (int r = 0; r < EPL; r++) v[r] = ((mkbits >> r) & 1u) ? PAD_VAL : xv[r];

    // ---- bitonic sort ----
    bsort<2>(v, t, buf);

    // ---- sorted column -> LDS ----
    __syncthreads();                           // protect buf vs last cross-stage readers
    *(float4*)(buf + t * EPL) = *(const float4*)v;
    __syncthreads();

    const float sl = (float)(wcnt[0] + wcnt[1] + wcnt[2] + wcnt[3]);

    // ---- quantiles (exact reference f32 arithmetic) -> squant ----
    #pragma unroll
    for (int s = 0; s < EPL; s++) {
        int qi = t + s * NT;
        if (qi < NQUANT) {
            float q = (float)(qi + 1) / 1000.0f;
            float idxf = q * (float)(NS - 1);
            int lo = (int)idxf;
            int hi = min(lo + 1, NS - 1);
            float frac = idxf - (float)lo;
            float a = buf[lo], c = buf[hi];
            squant[qi] = a + frac * (c - a);
        }
    }
    __syncthreads();

    // ---- support bucketize: 4 interleaved branchless 10-step searches ----
    int pos[EPL];
    #pragma unroll
    for (int r = 0; r < EPL; r++) pos[r] = 0;
    #pragma unroll
    for (int step = 512; step > 0; step >>= 1) {
        #pragma unroll
        for (int r = 0; r < EPL; r++) {
            int np = pos[r] + step;
            if (np <= NQUANT && squant[np - 1] <= xv[r]) pos[r] = np;
        }
    }

    float sum = 0.0f, sumsq = 0.0f;
    float vs[EPL];
    #pragma unroll
    for (int r = 0; r < EPL; r++) {
        float vv = ((mkbits >> r) & 1u) ? 0.0f : (float)pos[r] / sl;
        vs[r] = vv;
        sum += vv; sumsq += vv * vv;
    }
    #pragma unroll
    for (int o = 1; o < 64; o <<= 1) {
        sum   += __shfl_xor(sum, o, 64);
        sumsq += __shfl_xor(sumsq, o, 64);
    }
    if (lane == 0) { rstat[w] = sum; rstat[4 + w] = sumsq; }
    __syncthreads();
    const float S = rstat[0] + rstat[1] + rstat[2] + rstat[3];
    const float Q = rstat[4] + rstat[5] + rstat[6] + rstat[7];
    const float mean = S / sl;
    const float var = fmaxf(Q / sl - mean * mean, 0.0f);
    const float istd = (var > 0.0f) ? (1.0f / sqrtf(var)) : 0.0f;

    // ---- support output ----
    float* oscol = outS + (size_t)(b * NS) * NF + f;
    #pragma unroll
    for (int r = 0; r < EPL; r++)
        oscol[(t * EPL + r) * NF] = ((mkbits >> r) & 1u) ? 0.0f : (vs[r] - mean) * istd;

    // ---- query bucketize + output ----
    int posq[EPL];
    #pragma unroll
    for (int r = 0; r < EPL; r++) posq[r] = 0;
    #pragma unroll
    for (int step = 512; step > 0; step >>= 1) {
        #pragma unroll
        for (int r = 0; r < EPL; r++) {
            int np = posq[r] + step;
            if (np <= NQUANT && squant[np - 1] <= qv[r]) posq[r] = np;
        }
    }
    float* oqcol = outQ + (size_t)(b * NS) * NF + f;
    #pragma unroll
    for (int r = 0; r < EPL; r++)
        oqcol[(t * EPL + r) * NF] = ((float)posq[r] / sl - mean) * istd;
}

extern "C" void kernel_launch(void* const* d_in, const int* in_sizes, int n_in,
                              void* d_out, int out_size, void* d_ws, size_t ws_size,
                              hipStream_t stream) {
    const float* xs = (const float*)d_in[0];
    const float* xq = (const float*)d_in[1];
    const unsigned char* mraw = (const unsigned char*)d_in[2];
    float* out = (float*)d_out;

    fused<<<BATCH * NF, NT, 0, stream>>>(xs, xq, mraw,
                                         out, out + BATCH * NS * NF);
}

// Round 6
// 17.096 us; speedup vs baseline: 3.4354x; 1.1075x over previous
//
#include <hip/hip_runtime.h>

#define PAD_VAL 9999.0f
constexpr int BATCH = 8;
constexpr int NS = 1024;      // support rows
constexpr int NF = 32;        // features
constexpr int NQUANT = 999;   // quantile count
constexpr int NT = 512;       // threads per block (8 waves -> 2 waves/SIMD)
constexpr int EPL = 2;        // elements per lane (1024 / 512)

// Bitonic network, compile-time staged. EPL=2: all arrays register-resident.
// J>=128: cross-wave via double-buffered LDS (6 stages, 1 barrier each).
// 2<=J<=64: within-wave shfl_xor (m=1..32). J=1: in-register.
template<int K, int J, int P>
__device__ __forceinline__ void bstage(float (&v)[EPL], const int t,
                                       float* bufA, float* bufB) {
    if constexpr (J >= 64 * EPL) {            // J = 128/256/512: cross-wave
        float* buf = (P & 1) ? bufB : bufA;   // alternate buffers -> 1 barrier/stage
        *(float2*)(buf + t * EPL) = *(const float2*)v;
        __syncthreads();
        float o[EPL] __attribute__((aligned(8)));
        *(float2*)o = *(const float2*)(buf + ((t * EPL) ^ J));
        const bool keepmin = ((((t * EPL) & J) == 0) == (((t * EPL) & K) == 0));
        #pragma unroll
        for (int r = 0; r < EPL; r++)
            v[r] = keepmin ? fminf(v[r], o[r]) : fmaxf(v[r], o[r]);
        if constexpr (J > 1) bstage<K, J / 2, P + 1>(v, t, bufA, bufB);
    } else if constexpr (J >= EPL) {          // J = 2..64: lane xor m = J/2 (<=32)
        constexpr int m = J / EPL;
        const bool keepmin = ((((t * EPL) & J) == 0) == (((t * EPL) & K) == 0));
        #pragma unroll
        for (int r = 0; r < EPL; r++) {
            float o = __shfl_xor(v[r], m, 64);
            v[r] = keepmin ? fminf(v[r], o) : fmaxf(v[r], o);
        }
        if constexpr (J > 1) bstage<K, J / 2, P>(v, t, bufA, bufB);
    } else {                                   // J = 1: in-register swap
        const bool dir = (((t * EPL) & K) == 0);
        float a = v[0], c = v[1];
        float mn = fminf(a, c), mx = fmaxf(a, c);
        v[0] = dir ? mn : mx;
        v[1] = dir ? mx : mn;
    }
}

template<int K, int P>
__device__ __forceinline__ void bsort(float (&v)[EPL], const int t,
                                      float* bufA, float* bufB) {
    constexpr int nlds = (K <= 128) ? 0 : (K == 256 ? 1 : (K == 512 ? 2 : 3));
    bstage<K, K / 2, P>(v, t, bufA, bufB);
    if constexpr (K < NS) bsort<K * 2, P + nlds>(v, t, bufA, bufB);
}

__global__ __launch_bounds__(NT) void fused(const float* __restrict__ xs,
                                            const float* __restrict__ xq,
                                            const unsigned char* __restrict__ mraw,
                                            float* __restrict__ outS,
                                            float* __restrict__ outQ) {
    __shared__ float buf[NS];      // sort exchange A + sorted column
    __shared__ float squant[NS];   // sort exchange B, then quantile table
    __shared__ int   flags[2];
    __shared__ int   wcnt[8];
    __shared__ float rstat[16];

    const int t = threadIdx.x;
    const int lane = t & 63, w = t >> 6;
    // XCD-aware: bid%8 = XCD -> each XCD gets one batch (its 32 feature cols)
    const int b = blockIdx.x & 7, f = blockIdx.x >> 3;

    if (t < 2) flags[t] = 0;
    __syncthreads();

    // ---- mask layout detect: scan first 8 KiB (safe for byte-bool/int32/f32) ----
    {
        int l3f = 0, loff = 0;
        uint4 d = ((const uint4*)mraw)[t];
        unsigned ws4[4] = {d.x, d.y, d.z, d.w};
        #pragma unroll
        for (int c = 0; c < 4; c++) {
            if ((ws4[c] >> 24) == 0x3fu) l3f = 1;          // f32 1.0f top byte
            if ((ws4[c] & 0xFFFFFF00u) != 0u) loff = 1;    // nonzero high bytes
        }
        if (__ballot(l3f)  && lane == 0) atomicOr(&flags[0], 1);
        if (__ballot(loff) && lane == 0) atomicOr(&flags[1], 1);
    }
    __syncthreads();
    const int mode = flags[0] ? 2 : (flags[1] ? 1 : 0);  // 2=f32 1=byte 0=int32

    // ---- own 2 mask bits + per-wave seq_len partial ----
    unsigned mkbits = 0;
    if (mode == 1) {
        unsigned short mw = *(const unsigned short*)(mraw + b * NS + t * EPL);
        mkbits = ((mw & 0xffu) ? 1u : 0u) | ((mw >> 8) ? 2u : 0u);
    } else if (mode == 0) {
        uint2 d = ((const uint2*)mraw)[b * (NS / 2) + t];
        mkbits = (d.x != 0) | ((d.y != 0) << 1);
    } else {
        float2 d = ((const float2*)mraw)[b * (NS / 2) + t];
        mkbits = (d.x != 0.0f) | ((d.y != 0.0f) << 1);
    }
    {
        int cnt = EPL - __popc(mkbits);
        #pragma unroll
        for (int o = 1; o < 64; o <<= 1) cnt += __shfl_xor(cnt, o, 64);
        if (lane == 0) wcnt[w] = cnt;          // consumed after sort barriers
    }

    // ---- loads: support (kept) + query (early; in flight during sort) ----
    const float* xscol = xs + (size_t)(b * NS) * NF + f;
    const float* xqcol = xq + (size_t)(b * NS) * NF + f;
    float xv[EPL], qv[EPL];
    #pragma unroll
    for (int r = 0; r < EPL; r++) xv[r] = xscol[(t * EPL + r) * NF];
    #pragma unroll
    for (int r = 0; r < EPL; r++) qv[r] = xqcol[(t * EPL + r) * NF];

    float v[EPL] __attribute__((aligned(8)));
    #pragma unroll
    for (int r = 0; r < EPL; r++) v[r] = ((mkbits >> r) & 1u) ? PAD_VAL : xv[r];

    // ---- bitonic sort (register/shfl + 6 double-buffered LDS stages) ----
    bsort<2, 0>(v, t, buf, squant);

    // ---- sorted column -> buf ----
    __syncthreads();                           // protect buf vs last stage's readers
    *(float2*)(buf + t * EPL) = *(const float2*)v;
    __syncthreads();

    const float sl = (float)(wcnt[0] + wcnt[1] + wcnt[2] + wcnt[3] +
                             wcnt[4] + wcnt[5] + wcnt[6] + wcnt[7]);

    // ---- quantiles (exact reference f32 arithmetic) -> squant ----
    #pragma unroll
    for (int s = 0; s < EPL; s++) {
        int qi = t + s * NT;
        if (qi < NQUANT) {
            float q = (float)(qi + 1) / 1000.0f;
            float idxf = q * (float)(NS - 1);
            int lo = (int)idxf;
            int hi = min(lo + 1, NS - 1);
            float frac = idxf - (float)lo;
            float a = buf[lo], c = buf[hi];
            squant[qi] = a + frac * (c - a);
        }
    }
    __syncthreads();

    // ---- support + query searches, interleaved (4 streams of ILP) ----
    int pos[EPL], posq[EPL];
    #pragma unroll
    for (int r = 0; r < EPL; r++) { pos[r] = 0; posq[r] = 0; }
    #pragma unroll
    for (int step = 512; step > 0; step >>= 1) {
        #pragma unroll
        for (int r = 0; r < EPL; r++) {
            int np = pos[r] + step;
            if (np <= NQUANT && squant[np - 1] <= xv[r]) pos[r] = np;
            int nq = posq[r] + step;
            if (nq <= NQUANT && squant[nq - 1] <= qv[r]) posq[r] = nq;
        }
    }

    // ---- stats over support buckets ----
    float sum = 0.0f, sumsq = 0.0f;
    float vs[EPL];
    #pragma unroll
    for (int r = 0; r < EPL; r++) {
        float vv = ((mkbits >> r) & 1u) ? 0.0f : (float)pos[r] / sl;
        vs[r] = vv;
        sum += vv; sumsq += vv * vv;
    }
    #pragma unroll
    for (int o = 1; o < 64; o <<= 1) {
        sum   += __shfl_xor(sum, o, 64);
        sumsq += __shfl_xor(sumsq, o, 64);
    }
    if (lane == 0) { rstat[w] = sum; rstat[8 + w] = sumsq; }
    __syncthreads();
    float S = 0.0f, Q = 0.0f;
    #pragma unroll
    for (int i = 0; i < 8; i++) { S += rstat[i]; Q += rstat[8 + i]; }
    const float mean = S / sl;
    const float var = fmaxf(Q / sl - mean * mean, 0.0f);
    const float istd = (var > 0.0f) ? (1.0f / sqrtf(var)) : 0.0f;

    // ---- support output ----
    float* oscol = outS + (size_t)(b * NS) * NF + f;
    #pragma unroll
    for (int r = 0; r < EPL; r++)
        oscol[(t * EPL + r) * NF] = ((mkbits >> r) & 1u) ? 0.0f : (vs[r] - mean) * istd;

    // ---- query output ----
    float* oqcol = outQ + (size_t)(b * NS) * NF + f;
    #pragma unroll
    for (int r = 0; r < EPL; r++)
        oqcol[(t * EPL + r) * NF] = ((float)posq[r] / sl - mean) * istd;
}

extern "C" void kernel_launch(void* const* d_in, const int* in_sizes, int n_in,
                              void* d_out, int out_size, void* d_ws, size_t ws_size,
                              hipStream_t stream) {
    const float* xs = (const float*)d_in[0];
    const float* xq = (const float*)d_in[1];
    const unsigned char* mraw = (const unsigned char*)d_in[2];
    float* out = (float*)d_out;

    fused<<<BATCH * NF, NT, 0, stream>>>(xs, xq, mraw,
                                         out, out + BATCH * NS * NF);
}